// Round 11
// baseline (225.714 us; speedup 1.0000x reference)
//
#include <hip/hip_runtime.h>
#include <stdint.h>
#include <stddef.h>

// Problem constants
#define BSZ   4
#define TSEQ  2048
#define CDIM  1024
#define HEADS 16
#define DHEAD 64

typedef __attribute__((ext_vector_type(8))) short v8s;   // 8 bf16 (4 VGPRs)
typedef __attribute__((ext_vector_type(4))) float v4f;   // 4 f32 acc

__device__ __forceinline__ v4f mfma16(v8s a, v8s b, v4f c) {
  return __builtin_amdgcn_mfma_f32_16x16x32_bf16(a, b, c, 0, 0, 0);
}

// fp32 -> bf16 round-to-nearest-even
__device__ __forceinline__ short f2bf(float f) {
  union { float f; uint32_t u; } v; v.f = f;
  uint32_t r = (v.u + 0x7FFFu + ((v.u >> 16) & 1u)) >> 16;
  return (short)(uint16_t)r;
}

// pack two f32 -> one u32 of 2 bf16 (RNE), lo in [15:0]  (pure, non-volatile)
__device__ __forceinline__ uint32_t cvt_pk_bf16(float lo, float hi) {
  uint32_t r;
  asm("v_cvt_pk_bf16_f32 %0, %1, %2" : "=v"(r) : "v"(lo), "v"(hi));
  return r;
}

// async global->LDS, 16B per lane; dst is wave-uniform base (HW adds lane*16)
__device__ __forceinline__ void gl_lds16(const void* g, void* l) {
  __builtin_amdgcn_global_load_lds((const __attribute__((address_space(1))) void*)g,
                                   (__attribute__((address_space(3))) void*)l, 16, 0, 0);
}

#define BARw __builtin_amdgcn_s_barrier()
#define LGKM0 do { asm volatile("s_waitcnt lgkmcnt(0)" ::: "memory"); \
                   __builtin_amdgcn_sched_barrier(0); } while (0)

// ---------------- convert f32 -> bf16, 4 elems/thread ----------------
__global__ __launch_bounds__(256) void k_convert(const float* __restrict__ in,
                                                 short* __restrict__ out, int n) {
  int i = (blockIdx.x * 256 + threadIdx.x) * 4;
  if (i >= n) return;
  float4 v = *(const float4*)(in + i);
  short4 o;
  o.x = f2bf(v.x); o.y = f2bf(v.y); o.z = f2bf(v.z); o.w = f2bf(v.w);
  *(short4*)(out + i) = o;
}

// ---------------- transpose + convert: in[R][C] f32 -> out[C][R] bf16 ----------------
__global__ __launch_bounds__(256) void k_transpose_conv(const float* __restrict__ in,
                                                        short* __restrict__ out,
                                                        int R, int C) {
  __shared__ float tile[32][33];
  int c0 = blockIdx.x * 32, r0 = blockIdx.y * 32;
  int tx = threadIdx.x, ty = threadIdx.y;  // 32 x 8
  #pragma unroll
  for (int i = ty; i < 32; i += 8)
    tile[i][tx] = in[(size_t)(r0 + i) * C + c0 + tx];
  __syncthreads();
  #pragma unroll
  for (int i = ty; i < 32; i += 8)
    out[(size_t)(c0 + i) * R + r0 + tx] = f2bf(tile[tx][i]);
}

// ---------------- Vs[8192][1024] (sorted rows) -> Vt[B*H][64][2048] ----------------
__global__ __launch_bounds__(256) void k_vt(const short* __restrict__ Vs,
                                            short* __restrict__ Vt) {
  __shared__ short tl[64][72];
  const int t0 = blockIdx.x * 64, h = blockIdx.y, b = blockIdx.z;
  const int row = threadIdx.x >> 2, c4 = threadIdx.x & 3;
  const short* src = Vs + (size_t)(b * TSEQ + t0 + row) * CDIM + h * DHEAD;
  #pragma unroll
  for (int it = 0; it < 2; ++it) {
    int ch = c4 + it * 4;
    *(v8s*)&tl[row][ch * 8] = *(const v8s*)(src + ch * 8);
  }
  __syncthreads();
  short* dst = Vt + ((size_t)(b * HEADS + h) * DHEAD + row) * TSEQ + t0;
  #pragma unroll
  for (int it = 0; it < 2; ++it) {
    int ch = c4 + it * 4;
    v8s o;
    #pragma unroll
    for (int j = 0; j < 8; ++j) o[j] = tl[ch * 8 + j][row];
    *(v8s*)(dst + ch * 8) = o;
  }
}

// ---------------- GEMM1: 256x256 tile, BK=64, 8-wave, 8-phase counted-vmcnt ----------------
__global__ __launch_bounds__(512, 2) void k_gemm_qkv(const short* __restrict__ A,
                                                     const short* __restrict__ Wt,
                                                     const int* __restrict__ perm,
                                                     short* __restrict__ QK,
                                                     short* __restrict__ Vs) {
  __shared__ __align__(16) short Alds[2][256 * 64];
  __shared__ __align__(16) short Blds[2][256 * 64];
  const int l = threadIdx.x & 63, w = threadIdx.x >> 6;
  const int lr = l & 15, lg = l >> 4;
  const int wm = w >> 2, wn = w & 3;                 // 2 (M) x 4 (N) waves
  const int bid = blockIdx.x;
  const int swz = (bid & 7) * 48 + (bid >> 3);       // XCD-contiguous (384 % 8 == 0)
  const int by = swz / 12, bx = swz - by * 12;
  const int row0 = by * 256, col0 = bx * 256;

  v4f acc[8][4];
  #pragma unroll
  for (int i = 0; i < 8; ++i)
    #pragma unroll
    for (int j = 0; j < 4; ++j) acc[i][j] = (v4f){0.f, 0.f, 0.f, 0.f};

  const int rowoff = w * 8 + (l >> 3);
  const int gch = ((l & 7) ^ (l >> 3)) * 16;
  const char* Asrc = (const char*)A  + (size_t)(row0 + rowoff) * 2048 + gch;
  const char* Bsrc = (const char*)Wt + (size_t)(col0 + rowoff) * 2048 + gch;
  char* AL = (char*)&Alds[0][0];
  char* BL = (char*)&Blds[0][0];
  const int sdst = w * 1024;

  auto SA = [&](int kt, int h, int d) {
    char* dst = AL + d * 32768 + h * 16384 + sdst;
    const char* s = Asrc + (size_t)(h * 128) * 2048 + kt * 128;
    gl_lds16(s, dst);
    gl_lds16(s + (size_t)64 * 2048, dst + 8192);
  };
  auto SB = [&](int kt, int h, int d) {
    char* dst = BL + d * 32768 + h * 16384 + sdst;
    const char* s = Bsrc + (size_t)(h * 128) * 2048 + kt * 128;
    gl_lds16(s, dst);
    gl_lds16(s + (size_t)64 * 2048, dst + 8192);
  };

  const int rsw = (lr & 7) * 16;
  const int koff0 = (lg * 16) ^ rsw;
  const int koff1 = ((4 + lg) * 16) ^ rsw;
  const int abase = (wm * 128 + lr) * 128;
  const int bbase = (wn * 64 + lr) * 128;

  v8s af[4][2], bf[4][2];
  auto RDA = [&](int d, int ih) {
    const char* base = AL + d * 32768 + abase + ih * 8192;
    #pragma unroll
    for (int ii = 0; ii < 4; ++ii) {
      af[ii][0] = *(const v8s*)(base + ii * 2048 + koff0);
      af[ii][1] = *(const v8s*)(base + ii * 2048 + koff1);
    }
  };
  auto RDB = [&](int d) {
    const char* base = BL + d * 32768 + bbase;
    #pragma unroll
    for (int j = 0; j < 4; ++j) {
      bf[j][0] = *(const v8s*)(base + j * 2048 + koff0);
      bf[j][1] = *(const v8s*)(base + j * 2048 + koff1);
    }
  };

#define MMC(IH, JH)                                                            \
  do {                                                                         \
    __builtin_amdgcn_s_setprio(1);                                             \
    _Pragma("unroll")                                                          \
    for (int kk = 0; kk < 2; ++kk)                                             \
      _Pragma("unroll")                                                        \
      for (int ii = 0; ii < 4; ++ii)                                           \
        _Pragma("unroll")                                                      \
        for (int jj = 0; jj < 2; ++jj)                                         \
          acc[(IH) * 4 + ii][(JH) * 2 + jj] =                                  \
              mfma16(af[ii][kk], bf[(JH) * 2 + jj][kk],                        \
                     acc[(IH) * 4 + ii][(JH) * 2 + jj]);                       \
    __builtin_amdgcn_s_setprio(0);                                             \
  } while (0)

  SB(0, 0, 0); SB(0, 1, 0); SA(0, 0, 0); SA(0, 1, 0);
  SB(1, 0, 1); SB(1, 1, 1); SA(1, 0, 1); SA(1, 1, 1);
  asm volatile("s_waitcnt vmcnt(8)" ::: "memory");
  BARw;

  for (int i = 0; i < 8; ++i) {
    const int kt2 = 2 * i + 2, kt3 = 2 * i + 3;
    const bool st = (i < 7);
    RDA(0, 0); RDB(0);
    BARw; LGKM0; MMC(0, 0); BARw;
    if (st) SB(kt2, 0, 0);
    BARw; MMC(0, 1); BARw;
    RDA(0, 1); if (st) SB(kt2, 1, 0);
    BARw; LGKM0; MMC(1, 0); BARw;
    if (st) { SA(kt2, 0, 0); asm volatile("s_waitcnt vmcnt(6)" ::: "memory"); }
    else    { asm volatile("s_waitcnt vmcnt(0)" ::: "memory"); }
    BARw; MMC(1, 1); BARw;
    RDA(1, 0); RDB(1); if (st) SA(kt2, 1, 0);
    BARw; LGKM0; MMC(0, 0); BARw;
    if (st) SB(kt3, 0, 1);
    BARw; MMC(0, 1); BARw;
    RDA(1, 1); if (st) SB(kt3, 1, 1);
    BARw; LGKM0; MMC(1, 0); BARw;
    if (st) {
      SA(kt3, 0, 1); SA(kt3, 1, 1);
      asm volatile("s_waitcnt vmcnt(8)" ::: "memory");
    }
    BARw; MMC(1, 1); BARw;
  }
#undef MMC

  const int region = (col0 + wn * 64) >> 10;  // wave-uniform
  if (region == 0) {
    #pragma unroll
    for (int i = 0; i < 8; ++i) {
      int rowb = row0 + wm * 128 + i * 16 + lg * 4;
      #pragma unroll
      for (int j = 0; j < 4; ++j) {
        int col = col0 + wn * 64 + j * 16 + lr;
        #pragma unroll
        for (int r = 0; r < 4; ++r)
          QK[(size_t)(rowb + r) * 2048 + col] = f2bf(acc[i][j][r]);
      }
    }
  } else if (region == 1) {
    #pragma unroll
    for (int i = 0; i < 8; ++i) {
      int rowb = row0 + wm * 128 + i * 16 + lg * 4;
      int prow[4];
      #pragma unroll
      for (int r = 0; r < 4; ++r) {
        int t = (rowb + r) & 2047;
        prow[r] = ((rowb + r) - t) + perm[t];
      }
      #pragma unroll
      for (int j = 0; j < 4; ++j) {
        int col = col0 + wn * 64 + j * 16 + lr;
        #pragma unroll
        for (int r = 0; r < 4; ++r)
          QK[(size_t)prow[r] * 2048 + col] = f2bf(acc[i][j][r]);
      }
    }
  } else {
    #pragma unroll
    for (int i = 0; i < 8; ++i) {
      int rowb = row0 + wm * 128 + i * 16 + lg * 4;
      int prow[4];
      #pragma unroll
      for (int r = 0; r < 4; ++r) {
        int t = (rowb + r) & 2047;
        prow[r] = ((rowb + r) - t) + perm[t];
      }
      #pragma unroll
      for (int j = 0; j < 4; ++j) {
        int vc = col0 + wn * 64 + j * 16 + lr - 2048;
        #pragma unroll
        for (int r = 0; r < 4; ++r)
          Vs[(size_t)prow[r] * CDIM + vc] = f2bf(acc[i][j][r]);
      }
    }
  }
}

// ---------------- GEMM2 (single-barrier depth-2 pipeline): Obuf @ Woutt^T + bias ----------------
__global__ __launch_bounds__(256) void k_gemm_out(const short* __restrict__ A,
                                                  const short* __restrict__ Wt,
                                                  const float* __restrict__ bias,
                                                  float* __restrict__ out) {
  __shared__ __align__(16) short As[3][128 * 32];
  __shared__ __align__(16) short Bs[3][128 * 32];
  int l = threadIdx.x & 63, w = threadIdx.x >> 6;
  int lr = l & 15, lg = l >> 4;
  int row0 = blockIdx.y * 128, col0 = blockIdx.x * 128;
  int wr = (w >> 1) * 64, wc = (w & 1) * 64;
  v4f acc[4][4];
  #pragma unroll
  for (int i = 0; i < 4; ++i)
    #pragma unroll
    for (int j = 0; j < 4; ++j) acc[i][j] = (v4f){0.f, 0.f, 0.f, 0.f};

  const short* Ag = A  + (size_t)(row0 + w * 32 + (l >> 2)) * CDIM + (l & 3) * 8;
  const short* Bg = Wt + (size_t)(col0 + w * 32 + (l >> 2)) * CDIM + (l & 3) * 8;
  const int so = (w * 32) * 32;

  auto STAGE = [&](int it, int bf) {
    int k0 = it * 32;
    gl_lds16(Ag + k0, &As[bf][so]);
    gl_lds16(Ag + k0 + 16 * CDIM, &As[bf][so + 16 * 32]);
    gl_lds16(Bg + k0, &Bs[bf][so]);
    gl_lds16(Bg + k0 + 16 * CDIM, &Bs[bf][so + 16 * 32]);
  };

  auto BODY = [&](int it, int cur) {
    if (it < 31) asm volatile("s_waitcnt vmcnt(4)" ::: "memory");
    else         asm volatile("s_waitcnt vmcnt(0)" ::: "memory");
    __builtin_amdgcn_s_barrier();
    if (it < 30) STAGE(it + 2, (cur + 2) % 3);
    v8s af[4], bfr[4];
    #pragma unroll
    for (int i = 0; i < 4; ++i) af[i] = *(const v8s*)&As[cur][(wr + i * 16 + lr) * 32 + lg * 8];
    #pragma unroll
    for (int j = 0; j < 4; ++j) bfr[j] = *(const v8s*)&Bs[cur][(wc + j * 16 + lr) * 32 + lg * 8];
    __builtin_amdgcn_s_setprio(1);
    #pragma unroll
    for (int i = 0; i < 4; ++i)
      #pragma unroll
      for (int j = 0; j < 4; ++j) acc[i][j] = mfma16(af[i], bfr[j], acc[i][j]);
    __builtin_amdgcn_s_setprio(0);
  };

  STAGE(0, 0);
  STAGE(1, 1);
  for (int it = 0; it < 30; it += 3) {
    BODY(it, 0); BODY(it + 1, 1); BODY(it + 2, 2);
  }
  BODY(30, 0);
  BODY(31, 1);

  #pragma unroll
  for (int i = 0; i < 4; ++i) {
    int rowb = row0 + wr + i * 16 + lg * 4;
    #pragma unroll
    for (int j = 0; j < 4; ++j) {
      int col = col0 + wc + j * 16 + lr;
      float bv = bias[col];
      #pragma unroll
      for (int r = 0; r < 4; ++r)
        out[(size_t)(rowb + r) * CDIM + col] = acc[i][j][r] + bv;
    }
  }
}

// ---------------- flash attention: 8-wave 256-row blocks, depth-2 K/V prefetch ----------------
// QK: [8192][2048] bf16 (cols 0..1023 = Q unsorted, 1024..2047 = K sorted by perm)
// Vt: [B*H][64][2048] bf16 (kv positions sorted)
// grid: (H, T/256, B), block 512 (8 waves x 32 q-rows = 256 rows).
// K/V triple-buffered, staged 2 tiles ahead, counted vmcnt(2) (full drain only at tail).
// LDS: 3*(8K+8K) + 32K = 80KB -> 2 blocks/CU.
__global__ __launch_bounds__(512) void k_flash(const short* __restrict__ QK,
                                               const short* __restrict__ Vt,
                                               short* __restrict__ O) {
  __shared__ __align__(16) short Kbuf[3][64 * 64];
  __shared__ __align__(16) short Vbuf[3][64 * 64];
  __shared__ __align__(16) short plds[8][32 * 64];
  const int l = threadIdx.x & 63, w = threadIdx.x >> 6;
  const int lr = l & 15, lg = l >> 4;
  const int h = blockIdx.x, b = blockIdx.z;
  const int qb = (int)gridDim.y - 1 - (int)blockIdx.y;  // heavy blocks first
  const int q0 = qb * 256 + w * 32;                     // this wave's 32 q-rows
  const int nt = 4 * qb + 4;                            // KV tiles (block-uniform)
  const float C1 = 0.18033688011112042f;                // 0.125 * log2(e)

  // Q fragments (B-operand of swapped QK^T): 2 halves x 2 d-chunks
  const short* Qb = QK + (size_t)(b * TSEQ + q0) * 2048 + h * DHEAD;
  v8s aq[2][2];
  #pragma unroll
  for (int hh = 0; hh < 2; ++hh) {
    aq[hh][0] = *(const v8s*)(Qb + (size_t)(hh * 16 + lr) * 2048 + lg * 8);
    aq[hh][1] = *(const v8s*)(Qb + (size_t)(hh * 16 + lr) * 2048 + 32 + lg * 8);
  }

  v8s ones;
  #pragma unroll
  for (int i = 0; i < 8; ++i) ones[i] = (short)0x3F80;  // bf16 1.0

  v4f Oacc[2][4], sacc[2];
  #pragma unroll
  for (int hh = 0; hh < 2; ++hh) {
    sacc[hh] = (v4f){0.f, 0.f, 0.f, 0.f};
    #pragma unroll
    for (int d = 0; d < 4; ++d) Oacc[hh][d] = (v4f){0.f, 0.f, 0.f, 0.f};
  }

  // staging: 512 threads cover a full 64x64 tile in ONE gl_lds16 per tensor.
  const char* Ksrc = (const char*)QK + (size_t)(b * TSEQ) * 4096 + 2048 + (size_t)h * 128;
  const char* Vsrc = (const char*)Vt + (size_t)((b * HEADS + h) * DHEAD) * 4096;
  const int srow = w * 8 + (l >> 3);
  const int csw  = ((l & 7) ^ (l >> 3)) * 16;  // source-side chunk swizzle

  auto STAGE = [&](int kt, int bf) {
    char* kd = (char*)&Kbuf[bf][0] + w * 1024;
    char* vd = (char*)&Vbuf[bf][0] + w * 1024;
    gl_lds16(Ksrc + ((size_t)kt * 64 + srow) * 4096 + csw, kd);
    gl_lds16(Vsrc + (size_t)srow * 4096 + (size_t)kt * 128 + csw, vd);
  };

  STAGE(0, 0);
  if (nt > 1) STAGE(1, 1);
  const int x16 = (lr & 7) * 16;   // K/V read-side swizzle
  char* pb = (char*)&plds[w][0];
  const int e7 = lr & 7;           // P-buffer swizzle key

  for (int kt = 0; kt < nt; ++kt) {
    const int cur = kt % 3;
    if (kt + 1 < nt) asm volatile("s_waitcnt vmcnt(2)" ::: "memory");
    else             asm volatile("s_waitcnt vmcnt(0)" ::: "memory");
    __builtin_amdgcn_s_barrier();
    if (kt + 2 < nt) STAGE(kt + 2, (kt + 2) % 3);

    if (kt * 64 <= q0 + 31) {  // wave-active (some rows visible)
      const char* Kc = (const char*)&Kbuf[cur][0];
      const char* Vc = (const char*)&Vbuf[cur][0];

      // swapped QK^T: S[hh][g] = K_g . Q_hh  (lane: q=lr, k=16g+4lg+r)
      v4f S[2][4];
      __builtin_amdgcn_s_setprio(1);
      #pragma unroll
      for (int g = 0; g < 4; ++g) {
        const char* rp = Kc + (g * 16 + lr) * 128;
        v8s k0 = *(const v8s*)(rp + ((lg * 16) ^ x16));
        v8s k1 = *(const v8s*)(rp + ((64 + lg * 16) ^ x16));
        #pragma unroll
        for (int hh = 0; hh < 2; ++hh) {
          v4f z = (v4f){0.f, 0.f, 0.f, 0.f};
          z = mfma16(k0, aq[hh][0], z);
          S[hh][g] = mfma16(k1, aq[hh][1], z);
        }
      }
      __builtin_amdgcn_s_setprio(0);

      // softmax (fixed shift) + packed P store
      if (kt * 64 + 63 <= q0) {
        #pragma unroll
        for (int hh = 0; hh < 2; ++hh) {
          char* rowp = pb + (hh * 16 + lr) * 128 + 8 * (lg & 1);
          #pragma unroll
          for (int g = 0; g < 4; ++g) {
            float p0 = __builtin_exp2f(fmaf(S[hh][g][0], C1, -8.0f));
            float p1 = __builtin_exp2f(fmaf(S[hh][g][1], C1, -8.0f));
            float p2 = __builtin_exp2f(fmaf(S[hh][g][2], C1, -8.0f));
            float p3 = __builtin_exp2f(fmaf(S[hh][g][3], C1, -8.0f));
            uint2 wv;
            wv.x = cvt_pk_bf16(p0, p1);
            wv.y = cvt_pk_bf16(p2, p3);
            *(uint2*)(rowp + (((2 * g + (lg >> 1)) ^ e7) << 4)) = wv;
          }
        }
      } else {
        const int kg0 = kt * 64 + lg * 4;
        #pragma unroll
        for (int hh = 0; hh < 2; ++hh) {
          const int irow = q0 + hh * 16 + lr;
          char* rowp = pb + (hh * 16 + lr) * 128 + 8 * (lg & 1);
          #pragma unroll
          for (int g = 0; g < 4; ++g) {
            float p[4];
            #pragma unroll
            for (int r = 0; r < 4; ++r) {
              float e = __builtin_exp2f(fmaf(S[hh][g][r], C1, -8.0f));
              p[r] = (kg0 + g * 16 + r <= irow) ? e : 0.0f;
            }
            uint2 wv;
            wv.x = cvt_pk_bf16(p[0], p[1]);
            wv.y = cvt_pk_bf16(p[2], p[3]);
            *(uint2*)(rowp + (((2 * g + (lg >> 1)) ^ e7) << 4)) = wv;
          }
        }
      }
      asm volatile("s_waitcnt lgkmcnt(0)" ::: "memory");
      __builtin_amdgcn_sched_barrier(0);

      // P fragments (A-operand), row-sum MFMA, PV
      v8s ap[2][2];
      #pragma unroll
      for (int hh = 0; hh < 2; ++hh) {
        const char* rowp = pb + (hh * 16 + lr) * 128;
        ap[hh][0] = *(const v8s*)(rowp + ((lg ^ e7) << 4));
        ap[hh][1] = *(const v8s*)(rowp + (((4 + lg) ^ e7) << 4));
      }
      __builtin_amdgcn_s_setprio(1);
      #pragma unroll
      for (int hh = 0; hh < 2; ++hh) {
        sacc[hh] = mfma16(ap[hh][0], ones, sacc[hh]);
        sacc[hh] = mfma16(ap[hh][1], ones, sacc[hh]);
      }
      #pragma unroll
      for (int dk = 0; dk < 4; ++dk) {
        const char* vp = Vc + (dk * 16 + lr) * 128;
        v8s bv0 = *(const v8s*)(vp + ((lg * 16) ^ x16));
        v8s bv1 = *(const v8s*)(vp + ((64 + lg * 16) ^ x16));
        #pragma unroll
        for (int hh = 0; hh < 2; ++hh) {
          Oacc[hh][dk] = mfma16(ap[hh][0], bv0, Oacc[hh][dk]);
          Oacc[hh][dk] = mfma16(ap[hh][1], bv1, Oacc[hh][dk]);
        }
      }
      __builtin_amdgcn_s_setprio(0);
    }
  }

  // epilogue: normalize (sacc already in Oacc layout) and write
  #pragma unroll
  for (int hh = 0; hh < 2; ++hh) {
    float inv[4];
    #pragma unroll
    for (int r = 0; r < 4; ++r) inv[r] = 1.0f / sacc[hh][r];
    #pragma unroll
    for (int dk = 0; dk < 4; ++dk)
      #pragma unroll
      for (int r = 0; r < 4; ++r) {
        int row = q0 + hh * 16 + lg * 4 + r;
        int col = h * DHEAD + dk * 16 + lr;
        O[(size_t)(b * TSEQ + row) * CDIM + col] = f2bf(Oacc[hh][dk][r] * inv[r]);
      }
  }
}

extern "C" void kernel_launch(void* const* d_in, const int* in_sizes, int n_in,
                              void* d_out, int out_size, void* d_ws, size_t ws_size,
                              hipStream_t stream) {
  const float* x    = (const float*)d_in[0];
  const float* Wqkv = (const float*)d_in[1];
  const float* Wout = (const float*)d_in[2];
  const float* bout = (const float*)d_in[3];
  const int*   perm = (const int*)d_in[4];
  float* out = (float*)d_out;

  uint8_t* ws = (uint8_t*)d_ws;
  const size_t NTOK = (size_t)BSZ * TSEQ;              // 8192
  size_t off = 0;
  short* Xb    = (short*)(ws + off); off += NTOK * CDIM * 2;              // 16 MB
  short* Wqkvt = (short*)(ws + off); off += (size_t)3 * CDIM * CDIM * 2;  // 6 MB
  short* Woutt = (short*)(ws + off); off += (size_t)CDIM * CDIM * 2;      // 2 MB
  short* QKb   = (short*)(ws + off); off += NTOK * 2048 * 2;              // 32 MB
  short* Vtb   = (short*)(ws + off); off += NTOK * CDIM * 2;              // 16 MB
  short* Obuf  = (short*)(ws + off); off += NTOK * CDIM * 2;              // 16 MB
  short* Vsb   = Obuf;  // alias: Vs lifetime (GEMM1 -> k_vt) disjoint from Obuf (flash -> GEMM2)

  // 1. convert x -> bf16
  {
    int n = (int)(NTOK * CDIM);
    k_convert<<<n / (256 * 4), 256, 0, stream>>>(x, Xb, n);
  }
  // 2. transpose-convert weights
  k_transpose_conv<<<dim3(3 * CDIM / 32, CDIM / 32), dim3(32, 8), 0, stream>>>(Wqkv, Wqkvt, CDIM, 3 * CDIM);
  k_transpose_conv<<<dim3(CDIM / 32, CDIM / 32), dim3(32, 8), 0, stream>>>(Wout, Woutt, CDIM, CDIM);
  // 3. GEMM1 (256^2, 8-phase) -> QK (K sorted), Vs (sorted, row-major)
  k_gemm_qkv<<<dim3((NTOK / 256) * (3 * CDIM / 256)), 512, 0, stream>>>(Xb, Wqkvt, perm, QKb, Vsb);
  // 3b. transpose Vs -> Vt
  k_vt<<<dim3(TSEQ / 64, HEADS, BSZ), 256, 0, stream>>>(Vsb, Vtb);
  // 4. flash attention (8-wave blocks, depth-2 prefetch) -> Obuf
  k_flash<<<dim3(HEADS, TSEQ / 256, BSZ), 512, 0, stream>>>(QKb, Vtb, Obuf);
  // 5. GEMM2 + bias -> out
  k_gemm_out<<<dim3(CDIM / 128, NTOK / 128), 256, 0, stream>>>(Obuf, Woutt, bout, out);
}

// Round 13
// 201.247 us; speedup vs baseline: 1.1216x; 1.1216x over previous
//
#include <hip/hip_runtime.h>
#include <stdint.h>
#include <stddef.h>

// Problem constants
#define BSZ   4
#define TSEQ  2048
#define CDIM  1024
#define HEADS 16
#define DHEAD 64

typedef __attribute__((ext_vector_type(8))) short v8s;   // 8 bf16 (4 VGPRs)
typedef __attribute__((ext_vector_type(4))) float v4f;   // 4 f32 acc

__device__ __forceinline__ v4f mfma16(v8s a, v8s b, v4f c) {
  return __builtin_amdgcn_mfma_f32_16x16x32_bf16(a, b, c, 0, 0, 0);
}

// fp32 -> bf16 round-to-nearest-even
__device__ __forceinline__ short f2bf(float f) {
  union { float f; uint32_t u; } v; v.f = f;
  uint32_t r = (v.u + 0x7FFFu + ((v.u >> 16) & 1u)) >> 16;
  return (short)(uint16_t)r;
}

// pack two f32 -> one u32 of 2 bf16 (RNE), lo in [15:0]  (pure, non-volatile)
__device__ __forceinline__ uint32_t cvt_pk_bf16(float lo, float hi) {
  uint32_t r;
  asm("v_cvt_pk_bf16_f32 %0, %1, %2" : "=v"(r) : "v"(lo), "v"(hi));
  return r;
}

// async global->LDS, 16B per lane; dst is wave-uniform base (HW adds lane*16)
__device__ __forceinline__ void gl_lds16(const void* g, void* l) {
  __builtin_amdgcn_global_load_lds((const __attribute__((address_space(1))) void*)g,
                                   (__attribute__((address_space(3))) void*)l, 16, 0, 0);
}

#define BARw __builtin_amdgcn_s_barrier()
#define LGKM0 do { asm volatile("s_waitcnt lgkmcnt(0)" ::: "memory"); \
                   __builtin_amdgcn_sched_barrier(0); } while (0)

// ---------------- convert f32 -> bf16, 4 elems/thread ----------------
__global__ __launch_bounds__(256) void k_convert(const float* __restrict__ in,
                                                 short* __restrict__ out, int n) {
  int i = (blockIdx.x * 256 + threadIdx.x) * 4;
  if (i >= n) return;
  float4 v = *(const float4*)(in + i);
  short4 o;
  o.x = f2bf(v.x); o.y = f2bf(v.y); o.z = f2bf(v.z); o.w = f2bf(v.w);
  *(short4*)(out + i) = o;
}

// ---------------- transpose + convert: in[R][C] f32 -> out[C][R] bf16 ----------------
__global__ __launch_bounds__(256) void k_transpose_conv(const float* __restrict__ in,
                                                        short* __restrict__ out,
                                                        int R, int C) {
  __shared__ float tile[32][33];
  int c0 = blockIdx.x * 32, r0 = blockIdx.y * 32;
  int tx = threadIdx.x, ty = threadIdx.y;  // 32 x 8
  #pragma unroll
  for (int i = ty; i < 32; i += 8)
    tile[i][tx] = in[(size_t)(r0 + i) * C + c0 + tx];
  __syncthreads();
  #pragma unroll
  for (int i = ty; i < 32; i += 8)
    out[(size_t)(c0 + i) * R + r0 + tx] = f2bf(tile[tx][i]);
}

// ---------------- Vs[8192][1024] (sorted rows) -> Vt[B*H][64][2048] ----------------
__global__ __launch_bounds__(256) void k_vt(const short* __restrict__ Vs,
                                            short* __restrict__ Vt) {
  __shared__ short tl[64][72];
  const int t0 = blockIdx.x * 64, h = blockIdx.y, b = blockIdx.z;
  const int row = threadIdx.x >> 2, c4 = threadIdx.x & 3;
  const short* src = Vs + (size_t)(b * TSEQ + t0 + row) * CDIM + h * DHEAD;
  #pragma unroll
  for (int it = 0; it < 2; ++it) {
    int ch = c4 + it * 4;
    *(v8s*)&tl[row][ch * 8] = *(const v8s*)(src + ch * 8);
  }
  __syncthreads();
  short* dst = Vt + ((size_t)(b * HEADS + h) * DHEAD + row) * TSEQ + t0;
  #pragma unroll
  for (int it = 0; it < 2; ++it) {
    int ch = c4 + it * 4;
    v8s o;
    #pragma unroll
    for (int j = 0; j < 8; ++j) o[j] = tl[ch * 8 + j][row];
    *(v8s*)(dst + ch * 8) = o;
  }
}

// ---------------- GEMM1: 256x256 tile, BK=64, 8-wave, 8-phase counted-vmcnt ----------------
__global__ __launch_bounds__(512, 2) void k_gemm_qkv(const short* __restrict__ A,
                                                     const short* __restrict__ Wt,
                                                     const int* __restrict__ perm,
                                                     short* __restrict__ QK,
                                                     short* __restrict__ Vs) {
  __shared__ __align__(16) short Alds[2][256 * 64];
  __shared__ __align__(16) short Blds[2][256 * 64];
  const int l = threadIdx.x & 63, w = threadIdx.x >> 6;
  const int lr = l & 15, lg = l >> 4;
  const int wm = w >> 2, wn = w & 3;                 // 2 (M) x 4 (N) waves
  const int bid = blockIdx.x;
  const int swz = (bid & 7) * 48 + (bid >> 3);       // XCD-contiguous (384 % 8 == 0)
  const int by = swz / 12, bx = swz - by * 12;
  const int row0 = by * 256, col0 = bx * 256;

  v4f acc[8][4];
  #pragma unroll
  for (int i = 0; i < 8; ++i)
    #pragma unroll
    for (int j = 0; j < 4; ++j) acc[i][j] = (v4f){0.f, 0.f, 0.f, 0.f};

  const int rowoff = w * 8 + (l >> 3);
  const int gch = ((l & 7) ^ (l >> 3)) * 16;
  const char* Asrc = (const char*)A  + (size_t)(row0 + rowoff) * 2048 + gch;
  const char* Bsrc = (const char*)Wt + (size_t)(col0 + rowoff) * 2048 + gch;
  char* AL = (char*)&Alds[0][0];
  char* BL = (char*)&Blds[0][0];
  const int sdst = w * 1024;

  auto SA = [&](int kt, int h, int d) {
    char* dst = AL + d * 32768 + h * 16384 + sdst;
    const char* s = Asrc + (size_t)(h * 128) * 2048 + kt * 128;
    gl_lds16(s, dst);
    gl_lds16(s + (size_t)64 * 2048, dst + 8192);
  };
  auto SB = [&](int kt, int h, int d) {
    char* dst = BL + d * 32768 + h * 16384 + sdst;
    const char* s = Bsrc + (size_t)(h * 128) * 2048 + kt * 128;
    gl_lds16(s, dst);
    gl_lds16(s + (size_t)64 * 2048, dst + 8192);
  };

  const int rsw = (lr & 7) * 16;
  const int koff0 = (lg * 16) ^ rsw;
  const int koff1 = ((4 + lg) * 16) ^ rsw;
  const int abase = (wm * 128 + lr) * 128;
  const int bbase = (wn * 64 + lr) * 128;

  v8s af[4][2], bf[4][2];
  auto RDA = [&](int d, int ih) {
    const char* base = AL + d * 32768 + abase + ih * 8192;
    #pragma unroll
    for (int ii = 0; ii < 4; ++ii) {
      af[ii][0] = *(const v8s*)(base + ii * 2048 + koff0);
      af[ii][1] = *(const v8s*)(base + ii * 2048 + koff1);
    }
  };
  auto RDB = [&](int d) {
    const char* base = BL + d * 32768 + bbase;
    #pragma unroll
    for (int j = 0; j < 4; ++j) {
      bf[j][0] = *(const v8s*)(base + j * 2048 + koff0);
      bf[j][1] = *(const v8s*)(base + j * 2048 + koff1);
    }
  };

#define MMC(IH, JH)                                                            \
  do {                                                                         \
    __builtin_amdgcn_s_setprio(1);                                             \
    _Pragma("unroll")                                                          \
    for (int kk = 0; kk < 2; ++kk)                                             \
      _Pragma("unroll")                                                        \
      for (int ii = 0; ii < 4; ++ii)                                           \
        _Pragma("unroll")                                                      \
        for (int jj = 0; jj < 2; ++jj)                                         \
          acc[(IH) * 4 + ii][(JH) * 2 + jj] =                                  \
              mfma16(af[ii][kk], bf[(JH) * 2 + jj][kk],                        \
                     acc[(IH) * 4 + ii][(JH) * 2 + jj]);                       \
    __builtin_amdgcn_s_setprio(0);                                             \
  } while (0)

  SB(0, 0, 0); SB(0, 1, 0); SA(0, 0, 0); SA(0, 1, 0);
  SB(1, 0, 1); SB(1, 1, 1); SA(1, 0, 1); SA(1, 1, 1);
  asm volatile("s_waitcnt vmcnt(8)" ::: "memory");
  BARw;

  for (int i = 0; i < 8; ++i) {
    const int kt2 = 2 * i + 2, kt3 = 2 * i + 3;
    const bool st = (i < 7);
    RDA(0, 0); RDB(0);
    BARw; LGKM0; MMC(0, 0); BARw;
    if (st) SB(kt2, 0, 0);
    BARw; MMC(0, 1); BARw;
    RDA(0, 1); if (st) SB(kt2, 1, 0);
    BARw; LGKM0; MMC(1, 0); BARw;
    if (st) { SA(kt2, 0, 0); asm volatile("s_waitcnt vmcnt(6)" ::: "memory"); }
    else    { asm volatile("s_waitcnt vmcnt(0)" ::: "memory"); }
    BARw; MMC(1, 1); BARw;
    RDA(1, 0); RDB(1); if (st) SA(kt2, 1, 0);
    BARw; LGKM0; MMC(0, 0); BARw;
    if (st) SB(kt3, 0, 1);
    BARw; MMC(0, 1); BARw;
    RDA(1, 1); if (st) SB(kt3, 1, 1);
    BARw; LGKM0; MMC(1, 0); BARw;
    if (st) {
      SA(kt3, 0, 1); SA(kt3, 1, 1);
      asm volatile("s_waitcnt vmcnt(8)" ::: "memory");
    }
    BARw; MMC(1, 1); BARw;
  }
#undef MMC

  const int region = (col0 + wn * 64) >> 10;  // wave-uniform
  if (region == 0) {
    #pragma unroll
    for (int i = 0; i < 8; ++i) {
      int rowb = row0 + wm * 128 + i * 16 + lg * 4;
      #pragma unroll
      for (int j = 0; j < 4; ++j) {
        int col = col0 + wn * 64 + j * 16 + lr;
        #pragma unroll
        for (int r = 0; r < 4; ++r)
          QK[(size_t)(rowb + r) * 2048 + col] = f2bf(acc[i][j][r]);
      }
    }
  } else if (region == 1) {
    #pragma unroll
    for (int i = 0; i < 8; ++i) {
      int rowb = row0 + wm * 128 + i * 16 + lg * 4;
      int prow[4];
      #pragma unroll
      for (int r = 0; r < 4; ++r) {
        int t = (rowb + r) & 2047;
        prow[r] = ((rowb + r) - t) + perm[t];
      }
      #pragma unroll
      for (int j = 0; j < 4; ++j) {
        int col = col0 + wn * 64 + j * 16 + lr;
        #pragma unroll
        for (int r = 0; r < 4; ++r)
          QK[(size_t)prow[r] * 2048 + col] = f2bf(acc[i][j][r]);
      }
    }
  } else {
    #pragma unroll
    for (int i = 0; i < 8; ++i) {
      int rowb = row0 + wm * 128 + i * 16 + lg * 4;
      int prow[4];
      #pragma unroll
      for (int r = 0; r < 4; ++r) {
        int t = (rowb + r) & 2047;
        prow[r] = ((rowb + r) - t) + perm[t];
      }
      #pragma unroll
      for (int j = 0; j < 4; ++j) {
        int vc = col0 + wn * 64 + j * 16 + lr - 2048;
        #pragma unroll
        for (int r = 0; r < 4; ++r)
          Vs[(size_t)prow[r] * CDIM + vc] = f2bf(acc[i][j][r]);
      }
    }
  }
}

// ---------------- GEMM2 (single-barrier depth-2 pipeline): Obuf @ Woutt^T + bias ----------------
__global__ __launch_bounds__(256) void k_gemm_out(const short* __restrict__ A,
                                                  const short* __restrict__ Wt,
                                                  const float* __restrict__ bias,
                                                  float* __restrict__ out) {
  __shared__ __align__(16) short As[3][128 * 32];
  __shared__ __align__(16) short Bs[3][128 * 32];
  int l = threadIdx.x & 63, w = threadIdx.x >> 6;
  int lr = l & 15, lg = l >> 4;
  int row0 = blockIdx.y * 128, col0 = blockIdx.x * 128;
  int wr = (w >> 1) * 64, wc = (w & 1) * 64;
  v4f acc[4][4];
  #pragma unroll
  for (int i = 0; i < 4; ++i)
    #pragma unroll
    for (int j = 0; j < 4; ++j) acc[i][j] = (v4f){0.f, 0.f, 0.f, 0.f};

  const short* Ag = A  + (size_t)(row0 + w * 32 + (l >> 2)) * CDIM + (l & 3) * 8;
  const short* Bg = Wt + (size_t)(col0 + w * 32 + (l >> 2)) * CDIM + (l & 3) * 8;
  const int so = (w * 32) * 32;

  auto STAGE = [&](int it, int bf) {
    int k0 = it * 32;
    gl_lds16(Ag + k0, &As[bf][so]);
    gl_lds16(Ag + k0 + 16 * CDIM, &As[bf][so + 16 * 32]);
    gl_lds16(Bg + k0, &Bs[bf][so]);
    gl_lds16(Bg + k0 + 16 * CDIM, &Bs[bf][so + 16 * 32]);
  };

  auto BODY = [&](int it, int cur) {
    if (it < 31) asm volatile("s_waitcnt vmcnt(4)" ::: "memory");
    else         asm volatile("s_waitcnt vmcnt(0)" ::: "memory");
    __builtin_amdgcn_s_barrier();
    if (it < 30) STAGE(it + 2, (cur + 2) % 3);
    v8s af[4], bfr[4];
    #pragma unroll
    for (int i = 0; i < 4; ++i) af[i] = *(const v8s*)&As[cur][(wr + i * 16 + lr) * 32 + lg * 8];
    #pragma unroll
    for (int j = 0; j < 4; ++j) bfr[j] = *(const v8s*)&Bs[cur][(wc + j * 16 + lr) * 32 + lg * 8];
    __builtin_amdgcn_s_setprio(1);
    #pragma unroll
    for (int i = 0; i < 4; ++i)
      #pragma unroll
      for (int j = 0; j < 4; ++j) acc[i][j] = mfma16(af[i], bfr[j], acc[i][j]);
    __builtin_amdgcn_s_setprio(0);
  };

  STAGE(0, 0);
  STAGE(1, 1);
  for (int it = 0; it < 30; it += 3) {
    BODY(it, 0); BODY(it + 1, 1); BODY(it + 2, 2);
  }
  BODY(30, 0);
  BODY(31, 1);

  #pragma unroll
  for (int i = 0; i < 4; ++i) {
    int rowb = row0 + wr + i * 16 + lg * 4;
    #pragma unroll
    for (int j = 0; j < 4; ++j) {
      int col = col0 + wc + j * 16 + lr;
      float bv = bias[col];
      #pragma unroll
      for (int r = 0; r < 4; ++r)
        out[(size_t)(rowb + r) * CDIM + col] = acc[i][j][r] + bv;
    }
  }
}

// ---------------- flash attention: complementary-qb pairing, LDS P path ----------------
// QK: [8192][2048] bf16 (cols 0..1023 = Q unsorted, 1024..2047 = K sorted by perm)
// Vt: [B*H][64][2048] bf16 (kv positions sorted)
// grid: 512 x 1-D, block 512 (8 waves x 32 q-rows). Block n<256 -> heavy qb (7-qi),
// n>=256 -> light qb (qi): each CU's two resident blocks sum to qb=7 -> uniform 36
// tile-periods/CU (was 64 on y=0 CUs). XCD = n&7 = h&7 keeps per-XCD K/V ~4MB (L2-fit).
// K/V triple-buffered, staged 2 tiles ahead, counted vmcnt(2).
__global__ __launch_bounds__(512) void k_flash(const short* __restrict__ QK,
                                               const short* __restrict__ Vt,
                                               short* __restrict__ O) {
  __shared__ __align__(16) short Kbuf[3][64 * 64];
  __shared__ __align__(16) short Vbuf[3][64 * 64];
  __shared__ __align__(16) short plds[8][32 * 64];
  const int l = threadIdx.x & 63, w = threadIdx.x >> 6;
  const int lr = l & 15, lg = l >> 4;
  const int n = blockIdx.x;
  const int u = n & 255;
  const int h = u & 15;
  const int b = (u >> 4) & 3;
  const int qi = u >> 6;                       // 0..3
  const int qb = (n < 256) ? (7 - qi) : qi;    // complementary pairing
  const int q0 = qb * 256 + w * 32;            // this wave's 32 q-rows
  const int nt = 4 * qb + 4;                   // KV tiles (block-uniform)
  const float C1 = 0.18033688011112042f;       // 0.125 * log2(e)

  // Q fragments (B-operand of swapped QK^T): 2 halves x 2 d-chunks
  const short* Qb = QK + (size_t)(b * TSEQ + q0) * 2048 + h * DHEAD;
  v8s aq[2][2];
  #pragma unroll
  for (int hh = 0; hh < 2; ++hh) {
    aq[hh][0] = *(const v8s*)(Qb + (size_t)(hh * 16 + lr) * 2048 + lg * 8);
    aq[hh][1] = *(const v8s*)(Qb + (size_t)(hh * 16 + lr) * 2048 + 32 + lg * 8);
  }

  v8s ones;
  #pragma unroll
  for (int i = 0; i < 8; ++i) ones[i] = (short)0x3F80;  // bf16 1.0

  v4f Oacc[2][4], sacc[2];
  #pragma unroll
  for (int hh = 0; hh < 2; ++hh) {
    sacc[hh] = (v4f){0.f, 0.f, 0.f, 0.f};
    #pragma unroll
    for (int d = 0; d < 4; ++d) Oacc[hh][d] = (v4f){0.f, 0.f, 0.f, 0.f};
  }

  // staging: 512 threads cover a full 64x64 tile in ONE gl_lds16 per tensor.
  const char* Ksrc = (const char*)QK + (size_t)(b * TSEQ) * 4096 + 2048 + (size_t)h * 128;
  const char* Vsrc = (const char*)Vt + (size_t)((b * HEADS + h) * DHEAD) * 4096;
  const int srow = w * 8 + (l >> 3);
  const int csw  = ((l & 7) ^ (l >> 3)) * 16;  // source-side chunk swizzle

  auto STAGE = [&](int kt, int bf) {
    char* kd = (char*)&Kbuf[bf][0] + w * 1024;
    char* vd = (char*)&Vbuf[bf][0] + w * 1024;
    gl_lds16(Ksrc + ((size_t)kt * 64 + srow) * 4096 + csw, kd);
    gl_lds16(Vsrc + (size_t)srow * 4096 + (size_t)kt * 128 + csw, vd);
  };

  STAGE(0, 0);
  if (nt > 1) STAGE(1, 1);
  const int x16 = (lr & 7) * 16;   // K/V read-side swizzle
  char* pb = (char*)&plds[w][0];
  const int e7 = lr & 7;           // P-buffer swizzle key

  for (int kt = 0; kt < nt; ++kt) {
    const int cur = kt % 3;
    if (kt + 1 < nt) asm volatile("s_waitcnt vmcnt(2)" ::: "memory");
    else             asm volatile("s_waitcnt vmcnt(0)" ::: "memory");
    __builtin_amdgcn_s_barrier();
    if (kt + 2 < nt) STAGE(kt + 2, (kt + 2) % 3);

    if (kt * 64 <= q0 + 31) {  // wave-active (some rows visible)
      const char* Kc = (const char*)&Kbuf[cur][0];
      const char* Vc = (const char*)&Vbuf[cur][0];

      // swapped QK^T: S[hh][g] = K_g . Q_hh  (lane: q=lr, k=16g+4lg+r)
      v4f S[2][4];
      __builtin_amdgcn_s_setprio(1);
      #pragma unroll
      for (int g = 0; g < 4; ++g) {
        const char* rp = Kc + (g * 16 + lr) * 128;
        v8s k0 = *(const v8s*)(rp + ((lg * 16) ^ x16));
        v8s k1 = *(const v8s*)(rp + ((64 + lg * 16) ^ x16));
        #pragma unroll
        for (int hh = 0; hh < 2; ++hh) {
          v4f z = (v4f){0.f, 0.f, 0.f, 0.f};
          z = mfma16(k0, aq[hh][0], z);
          S[hh][g] = mfma16(k1, aq[hh][1], z);
        }
      }
      __builtin_amdgcn_s_setprio(0);

      // softmax (fixed shift) + packed P store to LDS
      if (kt * 64 + 63 <= q0) {
        #pragma unroll
        for (int hh = 0; hh < 2; ++hh) {
          char* rowp = pb + (hh * 16 + lr) * 128 + 8 * (lg & 1);
          #pragma unroll
          for (int g = 0; g < 4; ++g) {
            float p0 = __builtin_exp2f(fmaf(S[hh][g][0], C1, -8.0f));
            float p1 = __builtin_exp2f(fmaf(S[hh][g][1], C1, -8.0f));
            float p2 = __builtin_exp2f(fmaf(S[hh][g][2], C1, -8.0f));
            float p3 = __builtin_exp2f(fmaf(S[hh][g][3], C1, -8.0f));
            uint2 wv;
            wv.x = cvt_pk_bf16(p0, p1);
            wv.y = cvt_pk_bf16(p2, p3);
            *(uint2*)(rowp + (((2 * g + (lg >> 1)) ^ e7) << 4)) = wv;
          }
        }
      } else {
        const int kg0 = kt * 64 + lg * 4;
        #pragma unroll
        for (int hh = 0; hh < 2; ++hh) {
          const int irow = q0 + hh * 16 + lr;
          char* rowp = pb + (hh * 16 + lr) * 128 + 8 * (lg & 1);
          #pragma unroll
          for (int g = 0; g < 4; ++g) {
            float p[4];
            #pragma unroll
            for (int r = 0; r < 4; ++r) {
              float e = __builtin_exp2f(fmaf(S[hh][g][r], C1, -8.0f));
              p[r] = (kg0 + g * 16 + r <= irow) ? e : 0.0f;
            }
            uint2 wv;
            wv.x = cvt_pk_bf16(p[0], p[1]);
            wv.y = cvt_pk_bf16(p[2], p[3]);
            *(uint2*)(rowp + (((2 * g + (lg >> 1)) ^ e7) << 4)) = wv;
          }
        }
      }
      asm volatile("s_waitcnt lgkmcnt(0)" ::: "memory");
      __builtin_amdgcn_sched_barrier(0);

      // P fragments (A-operand), row-sum MFMA, PV
      v8s ap[2][2];
      #pragma unroll
      for (int hh = 0; hh < 2; ++hh) {
        const char* rowp = pb + (hh * 16 + lr) * 128;
        ap[hh][0] = *(const v8s*)(rowp + ((lg ^ e7) << 4));
        ap[hh][1] = *(const v8s*)(rowp + (((4 + lg) ^ e7) << 4));
      }
      __builtin_amdgcn_s_setprio(1);
      #pragma unroll
      for (int hh = 0; hh < 2; ++hh) {
        sacc[hh] = mfma16(ap[hh][0], ones, sacc[hh]);
        sacc[hh] = mfma16(ap[hh][1], ones, sacc[hh]);
      }
      #pragma unroll
      for (int dk = 0; dk < 4; ++dk) {
        const char* vp = Vc + (dk * 16 + lr) * 128;
        v8s bv0 = *(const v8s*)(vp + ((lg * 16) ^ x16));
        v8s bv1 = *(const v8s*)(vp + ((64 + lg * 16) ^ x16));
        #pragma unroll
        for (int hh = 0; hh < 2; ++hh) {
          Oacc[hh][dk] = mfma16(ap[hh][0], bv0, Oacc[hh][dk]);
          Oacc[hh][dk] = mfma16(ap[hh][1], bv1, Oacc[hh][dk]);
        }
      }
      __builtin_amdgcn_s_setprio(0);
    }
  }

  // epilogue: normalize (sacc already in Oacc layout) and write
  #pragma unroll
  for (int hh = 0; hh < 2; ++hh) {
    float inv[4];
    #pragma unroll
    for (int r = 0; r < 4; ++r) inv[r] = 1.0f / sacc[hh][r];
    #pragma unroll
    for (int dk = 0; dk < 4; ++dk)
      #pragma unroll
      for (int r = 0; r < 4; ++r) {
        int row = q0 + hh * 16 + lg * 4 + r;
        int col = h * DHEAD + dk * 16 + lr;
        O[(size_t)(b * TSEQ + row) * CDIM + col] = f2bf(Oacc[hh][dk][r] * inv[r]);
      }
  }
}

extern "C" void kernel_launch(void* const* d_in, const int* in_sizes, int n_in,
                              void* d_out, int out_size, void* d_ws, size_t ws_size,
                              hipStream_t stream) {
  const float* x    = (const float*)d_in[0];
  const float* Wqkv = (const float*)d_in[1];
  const float* Wout = (const float*)d_in[2];
  const float* bout = (const float*)d_in[3];
  const int*   perm = (const int*)d_in[4];
  float* out = (float*)d_out;

  uint8_t* ws = (uint8_t*)d_ws;
  const size_t NTOK = (size_t)BSZ * TSEQ;              // 8192
  size_t off = 0;
  short* Xb    = (short*)(ws + off); off += NTOK * CDIM * 2;              // 16 MB
  short* Wqkvt = (short*)(ws + off); off += (size_t)3 * CDIM * CDIM * 2;  // 6 MB
  short* Woutt = (short*)(ws + off); off += (size_t)CDIM * CDIM * 2;      // 2 MB
  short* QKb   = (short*)(ws + off); off += NTOK * 2048 * 2;              // 32 MB
  short* Vtb   = (short*)(ws + off); off += NTOK * CDIM * 2;              // 16 MB
  short* Obuf  = (short*)(ws + off); off += NTOK * CDIM * 2;              // 16 MB
  short* Vsb   = Obuf;  // alias: Vs lifetime (GEMM1 -> k_vt) disjoint from Obuf (flash -> GEMM2)

  // 1. convert x -> bf16
  {
    int n = (int)(NTOK * CDIM);
    k_convert<<<n / (256 * 4), 256, 0, stream>>>(x, Xb, n);
  }
  // 2. transpose-convert weights
  k_transpose_conv<<<dim3(3 * CDIM / 32, CDIM / 32), dim3(32, 8), 0, stream>>>(Wqkv, Wqkvt, CDIM, 3 * CDIM);
  k_transpose_conv<<<dim3(CDIM / 32, CDIM / 32), dim3(32, 8), 0, stream>>>(Wout, Woutt, CDIM, CDIM);
  // 3. GEMM1 (256^2, 8-phase) -> QK (K sorted), Vs (sorted, row-major)
  k_gemm_qkv<<<dim3((NTOK / 256) * (3 * CDIM / 256)), 512, 0, stream>>>(Xb, Wqkvt, perm, QKb, Vsb);
  // 3b. transpose Vs -> Vt
  k_vt<<<dim3(TSEQ / 64, HEADS, BSZ), 256, 0, stream>>>(Vsb, Vtb);
  // 4. flash attention (complementary-qb pairing, LDS P path) -> Obuf
  k_flash<<<dim3(512), 512, 0, stream>>>(QKb, Vtb, Obuf);
  // 5. GEMM2 + bias -> out
  k_gemm_out<<<dim3(CDIM / 128, NTOK / 128), 256, 0, stream>>>(Obuf, Woutt, bout, out);
}